// Round 2
// baseline (165.541 us; speedup 1.0000x reference)
//
#include <hip/hip_runtime.h>
#include <cstdint>
#include <cstddef>

// Problem constants
#define B_DIM 4096   // batch (GEMM M)
#define S_DIM 2048   // states (GEMM N)
#define D_DIM 2496   // feature dim (GEMM K) = 78 * 32

// GEMM tiling: 128x64 tile, BK=32, 4 waves each owning 64x32 (4x2 MFMA 16x16x32).
// 128x128 gave only 512 blocks = 2 blocks/CU (Occupancy 18%, MfmaUtil 25%);
// 128x64 doubles resident blocks to 4/CU to cover the per-iter barrier drain.
#define BM 128
#define BN 64
#define BK 32

typedef __attribute__((ext_vector_type(8))) short short8;
typedef __attribute__((ext_vector_type(4))) float f32x4;

// ---------------------------------------------------------------------------
// fp32 -> bf16 round-to-nearest-even (inputs are positive uniforms; no NaN)
__device__ __forceinline__ unsigned short f2bf(float f) {
    union { float f; unsigned int u; } v; v.f = f;
    unsigned int r = (v.u + 0x7fffu + ((v.u >> 16) & 1u)) >> 16;
    return (unsigned short)r;
}

struct __attribute__((aligned(16))) us8 { unsigned short h[8]; };

// ---------------------------------------------------------------------------
// Prep, wave-per-row: each 64-lane wave converts one row to bf16 and computes
// its fp32 squared norm via shuffle reduce. No LDS, no barriers. 16 B/lane
// loads (2x float4) and 16 B/lane stores (bf16 x8). 4 rows per 256-thr block.
__global__ __launch_bounds__(256) void prep_kernel(
    const float* __restrict__ X, const float* __restrict__ Mx,
    unsigned short* __restrict__ Xb, unsigned short* __restrict__ Mb,
    float* __restrict__ xsq, float* __restrict__ msq)
{
    const int lane = threadIdx.x & 63;
    const int row  = blockIdx.x * 4 + (threadIdx.x >> 6);

    const float* src; unsigned short* dst; float* sq;
    if (row < B_DIM) {
        src = X + (size_t)row * D_DIM; dst = Xb + (size_t)row * D_DIM; sq = xsq + row;
    } else {
        const int r = row - B_DIM;
        src = Mx + (size_t)r * D_DIM; dst = Mb + (size_t)r * D_DIM; sq = msq + r;
    }

    const float4* s4 = (const float4*)src;
    us8* d8 = (us8*)dst;
    float acc = 0.f;
    // D_DIM/8 = 312 us8-chunks per row; lane-strided by 64 (4-5 iters/lane)
    for (int i = lane; i < D_DIM / 8; i += 64) {
        float4 a = s4[2 * i], b = s4[2 * i + 1];
        acc += a.x * a.x + a.y * a.y + a.z * a.z + a.w * a.w;
        acc += b.x * b.x + b.y * b.y + b.z * b.z + b.w * b.w;
        us8 h;
        h.h[0] = f2bf(a.x); h.h[1] = f2bf(a.y); h.h[2] = f2bf(a.z); h.h[3] = f2bf(a.w);
        h.h[4] = f2bf(b.x); h.h[5] = f2bf(b.y); h.h[6] = f2bf(b.z); h.h[7] = f2bf(b.w);
        d8[i] = h;
    }
    #pragma unroll
    for (int off = 32; off > 0; off >>= 1)
        acc += __shfl_down(acc, off, 64);
    if (lane == 0) *sq = acc;
}

// ---------------------------------------------------------------------------
// global -> LDS direct (async) load, 16 B per lane. LDS dest is wave-uniform
// base + lane*16 (hardware-defined scatter) — LDS layout must be contiguous
// in lane order, so no padding on the BK dimension.
__device__ __forceinline__ void gld_lds16(const unsigned short* g, unsigned short* l) {
    __builtin_amdgcn_global_load_lds(
        (const __attribute__((address_space(1))) unsigned int*)g,
        (__attribute__((address_space(3))) unsigned int*)l,
        16, 0, 0);
}

// ---------------------------------------------------------------------------
// C[row,col] = (2*sum_k A[row,k]*B[col,k] - xsq[row] - msq[col]) / 500
// A: [4096, 2496] bf16 row-major; Bt: [2048, 2496] bf16 row-major (NT GEMM).
__global__ __launch_bounds__(256) void gemm_kernel(
    const unsigned short* __restrict__ A,
    const unsigned short* __restrict__ Bt,
    const float* __restrict__ xsq, const float* __restrict__ msq,
    float* __restrict__ C)
{
    constexpr int N = S_DIM;
    constexpr int K = D_DIM;

    __shared__ __align__(16) unsigned short As[BM * BK];  // 8 KB
    __shared__ __align__(16) unsigned short Bs[BN * BK];  // 4 KB

    const int tid  = threadIdx.x;
    const int lane = tid & 63;
    const int wave = tid >> 6;       // 4 waves
    const int wm = wave >> 1;        // wave row (0..1) -> 64 rows
    const int wn = wave & 1;         // wave col (0..1) -> 32 cols
    const int bm = blockIdx.y;
    const int bn = blockIdx.x;

    // Staging: one gld_lds16 issue covers 16 rows x 32 cols bf16
    // (64 lanes x 16 B). Each wave: 2 A-issues (its 32-row chunk) +
    // 1 B-issue (its 16-row chunk). Lane i -> row (lane>>2), k-seg (lane&3)*8;
    // LDS lands at base + lane*16 == row*64B + seg*16B (contiguous, unpadded).
    const int srowA = wave * 32 + (lane >> 2);
    const int srowB = wave * 16 + (lane >> 2);
    const int skk   = (lane & 3) * 8;
    const unsigned short* gA = A  + (size_t)(bm * BM + srowA) * K + skk;
    const unsigned short* gB = Bt + (size_t)(bn * BN + srowB) * K + skk;
    unsigned short* lA0 = &As[(wave * 32     ) * BK];
    unsigned short* lA1 = &As[(wave * 32 + 16) * BK];
    unsigned short* lB0 = &Bs[(wave * 16     ) * BK];

    f32x4 acc[4][2] = {};

    const int ko = (lane >> 4) * 8;  // A/B frag: k = quad*8 + j
    const int fr = lane & 15;        // A/B frag: m (or n) = lane & 15

    for (int k0 = 0; k0 < K; k0 += BK) {
        __syncthreads();   // previous tile fully consumed
        gld_lds16(gA,                  lA0);
        gld_lds16(gA + (size_t)16 * K, lA1);
        gld_lds16(gB,                  lB0);
        gA += BK; gB += BK;
        __syncthreads();   // compiler drains vmcnt(0) before barrier

        short8 af[4], bfr[2];
        #pragma unroll
        for (int i = 0; i < 4; ++i)
            af[i]  = *(const short8*)&As[(wm * 64 + i * 16 + fr) * BK + ko];
        #pragma unroll
        for (int i = 0; i < 2; ++i)
            bfr[i] = *(const short8*)&Bs[(wn * 32 + i * 16 + fr) * BK + ko];
        #pragma unroll
        for (int mi = 0; mi < 4; ++mi)
            #pragma unroll
            for (int ni = 0; ni < 2; ++ni)
                acc[mi][ni] = __builtin_amdgcn_mfma_f32_16x16x32_bf16(
                    af[mi], bfr[ni], acc[mi][ni], 0, 0, 0);
    }

    // Epilogue. C/D layout: col = lane&15, row = (lane>>4)*4 + reg (m89/m91).
    const int row0 = bm * BM + wm * 64 + (lane >> 4) * 4;
    const int col0 = bn * BN + wn * 32 + fr;
    float ms[2];
    #pragma unroll
    for (int ni = 0; ni < 2; ++ni) ms[ni] = msq[col0 + ni * 16];
    #pragma unroll
    for (int mi = 0; mi < 4; ++mi) {
        #pragma unroll
        for (int r = 0; r < 4; ++r) {
            const int row = row0 + mi * 16 + r;
            const float xs = xsq[row];
            #pragma unroll
            for (int ni = 0; ni < 2; ++ni) {
                const float v = (2.0f * acc[mi][ni][r] - xs - ms[ni]) * (1.0f / 500.0f);
                C[(size_t)row * N + col0 + ni * 16] = v;
            }
        }
    }
}

// ---------------------------------------------------------------------------
extern "C" void kernel_launch(void* const* d_in, const int* in_sizes, int n_in,
                              void* d_out, int out_size, void* d_ws, size_t ws_size,
                              hipStream_t stream) {
    const float* X  = (const float*)d_in[0];  // [4096, 2496]
    const float* Mx = (const float*)d_in[1];  // [2048, 2496]
    float* out = (float*)d_out;               // [4096, 2048]

    // Workspace layout (~30.7 MB): Xb bf16 | Mb bf16 | xsq f32 | msq f32
    unsigned short* Xb = (unsigned short*)d_ws;
    unsigned short* Mb = Xb + (size_t)B_DIM * D_DIM;
    float* xsq = (float*)(Mb + (size_t)S_DIM * D_DIM);
    float* msq = xsq + B_DIM;

    prep_kernel<<<(B_DIM + S_DIM) / 4, 256, 0, stream>>>(X, Mx, Xb, Mb, xsq, msq);

    dim3 grid(S_DIM / BN, B_DIM / BM);  // (32, 32) = 1024 blocks -> 4/CU
    gemm_kernel<<<grid, 256, 0, stream>>>(Xb, Mb, xsq, msq, out);
}

// Round 3
// 154.334 us; speedup vs baseline: 1.0726x; 1.0726x over previous
//
#include <hip/hip_runtime.h>
#include <cstdint>
#include <cstddef>

// Problem constants
#define B_DIM 4096   // batch (GEMM M)
#define S_DIM 2048   // states (GEMM N)
#define D_DIM 2496   // feature dim (GEMM K) = 78 * 32

// GEMM tiling: 128x128 tile (R1's staging economics), BK=32, but 512 threads =
// 8 waves/block, each wave 64x32 (4x2 MFMA 16x16x32). Grid 512 blocks ->
// 2 blocks/CU x 8 waves = 4 waves/SIMD (vs R1's 2) to cover the barrier drain
// WITHOUT changing FLOPs-per-staged-byte (R2's mistake: BN=64 cut that 1.5x).
#define BM 128
#define BN 128
#define BK 32

typedef __attribute__((ext_vector_type(8))) short short8;
typedef __attribute__((ext_vector_type(4))) float f32x4;

// ---------------------------------------------------------------------------
// fp32 -> bf16 round-to-nearest-even (inputs are positive uniforms; no NaN)
__device__ __forceinline__ unsigned short f2bf(float f) {
    union { float f; unsigned int u; } v; v.f = f;
    unsigned int r = (v.u + 0x7fffu + ((v.u >> 16) & 1u)) >> 16;
    return (unsigned short)r;
}

struct __attribute__((aligned(16))) us8 { unsigned short h[8]; };

// ---------------------------------------------------------------------------
// Prep, wave-per-row: each 64-lane wave converts one row to bf16 and computes
// its fp32 squared norm via shuffle reduce. No LDS, no barriers.
__global__ __launch_bounds__(256) void prep_kernel(
    const float* __restrict__ X, const float* __restrict__ Mx,
    unsigned short* __restrict__ Xb, unsigned short* __restrict__ Mb,
    float* __restrict__ xsq, float* __restrict__ msq)
{
    const int lane = threadIdx.x & 63;
    const int row  = blockIdx.x * 4 + (threadIdx.x >> 6);

    const float* src; unsigned short* dst; float* sq;
    if (row < B_DIM) {
        src = X + (size_t)row * D_DIM; dst = Xb + (size_t)row * D_DIM; sq = xsq + row;
    } else {
        const int r = row - B_DIM;
        src = Mx + (size_t)r * D_DIM; dst = Mb + (size_t)r * D_DIM; sq = msq + r;
    }

    const float4* s4 = (const float4*)src;
    us8* d8 = (us8*)dst;
    float acc = 0.f;
    for (int i = lane; i < D_DIM / 8; i += 64) {
        float4 a = s4[2 * i], b = s4[2 * i + 1];
        acc += a.x * a.x + a.y * a.y + a.z * a.z + a.w * a.w;
        acc += b.x * b.x + b.y * b.y + b.z * b.z + b.w * b.w;
        us8 h;
        h.h[0] = f2bf(a.x); h.h[1] = f2bf(a.y); h.h[2] = f2bf(a.z); h.h[3] = f2bf(a.w);
        h.h[4] = f2bf(b.x); h.h[5] = f2bf(b.y); h.h[6] = f2bf(b.z); h.h[7] = f2bf(b.w);
        d8[i] = h;
    }
    #pragma unroll
    for (int off = 32; off > 0; off >>= 1)
        acc += __shfl_down(acc, off, 64);
    if (lane == 0) *sq = acc;
}

// ---------------------------------------------------------------------------
// global -> LDS direct (async) load, 16 B per lane; dest = wave-uniform base +
// lane*16 (no per-lane scatter), so LDS layout is contiguous in lane order.
__device__ __forceinline__ void gld_lds16(const unsigned short* g, unsigned short* l) {
    __builtin_amdgcn_global_load_lds(
        (const __attribute__((address_space(1))) unsigned int*)g,
        (__attribute__((address_space(3))) unsigned int*)l,
        16, 0, 0);
}

// ---------------------------------------------------------------------------
// C[row,col] = (2*sum_k A[row,k]*B[col,k] - xsq[row] - msq[col]) / 500
// A: [4096, 2496] bf16 row-major; Bt: [2048, 2496] bf16 row-major (NT GEMM).
__global__ __launch_bounds__(512, 4) void gemm_kernel(
    const unsigned short* __restrict__ A,
    const unsigned short* __restrict__ Bt,
    const float* __restrict__ xsq, const float* __restrict__ msq,
    float* __restrict__ C)
{
    constexpr int N = S_DIM;
    constexpr int K = D_DIM;

    __shared__ __align__(16) unsigned short As[BM * BK];  // 8 KB
    __shared__ __align__(16) unsigned short Bs[BN * BK];  // 8 KB

    const int tid  = threadIdx.x;
    const int lane = tid & 63;
    const int wave = tid >> 6;       // 8 waves
    const int wm = wave >> 2;        // wave row (0..1) -> 64 rows
    const int wn = wave & 3;         // wave col (0..3) -> 32 cols
    const int bm = blockIdx.y;
    const int bn = blockIdx.x;

    // Staging: one gld_lds16 issue covers 16 rows x 32 k (64 lanes x 16 B).
    // Each of 8 waves issues 1 A-chunk + 1 B-chunk (its 16-row slice).
    const int srow = wave * 16 + (lane >> 2);
    const int skk  = (lane & 3) * 8;
    const unsigned short* gA = A  + (size_t)(bm * BM + srow) * K + skk;
    const unsigned short* gB = Bt + (size_t)(bn * BN + srow) * K + skk;
    unsigned short* lA = &As[(wave * 16) * BK];
    unsigned short* lB = &Bs[(wave * 16) * BK];

    f32x4 acc[4][2] = {};

    const int ko = (lane >> 4) * 8;  // A/B frag: k = quad*8 + j
    const int fr = lane & 15;        // A/B frag: m (or n) = lane & 15

    for (int k0 = 0; k0 < K; k0 += BK) {
        __syncthreads();   // previous tile fully consumed
        gld_lds16(gA, lA);
        gld_lds16(gB, lB);
        gA += BK; gB += BK;
        __syncthreads();   // compiler drains vmcnt(0) before barrier

        short8 af[4], bfr[2];
        #pragma unroll
        for (int i = 0; i < 4; ++i)
            af[i]  = *(const short8*)&As[(wm * 64 + i * 16 + fr) * BK + ko];
        #pragma unroll
        for (int i = 0; i < 2; ++i)
            bfr[i] = *(const short8*)&Bs[(wn * 32 + i * 16 + fr) * BK + ko];
        #pragma unroll
        for (int mi = 0; mi < 4; ++mi)
            #pragma unroll
            for (int ni = 0; ni < 2; ++ni)
                acc[mi][ni] = __builtin_amdgcn_mfma_f32_16x16x32_bf16(
                    af[mi], bfr[ni], acc[mi][ni], 0, 0, 0);
    }

    // Epilogue. C/D layout: col = lane&15, row = (lane>>4)*4 + reg (m89/m91).
    const int row0 = bm * BM + wm * 64 + (lane >> 4) * 4;
    const int col0 = bn * BN + wn * 32 + fr;
    float ms[2];
    #pragma unroll
    for (int ni = 0; ni < 2; ++ni) ms[ni] = msq[col0 + ni * 16];
    #pragma unroll
    for (int mi = 0; mi < 4; ++mi) {
        #pragma unroll
        for (int r = 0; r < 4; ++r) {
            const int row = row0 + mi * 16 + r;
            const float xs = xsq[row];
            #pragma unroll
            for (int ni = 0; ni < 2; ++ni) {
                const float v = (2.0f * acc[mi][ni][r] - xs - ms[ni]) * (1.0f / 500.0f);
                C[(size_t)row * N + col0 + ni * 16] = v;
            }
        }
    }
}

// ---------------------------------------------------------------------------
extern "C" void kernel_launch(void* const* d_in, const int* in_sizes, int n_in,
                              void* d_out, int out_size, void* d_ws, size_t ws_size,
                              hipStream_t stream) {
    const float* X  = (const float*)d_in[0];  // [4096, 2496]
    const float* Mx = (const float*)d_in[1];  // [2048, 2496]
    float* out = (float*)d_out;               // [4096, 2048]

    // Workspace layout (~30.7 MB): Xb bf16 | Mb bf16 | xsq f32 | msq f32
    unsigned short* Xb = (unsigned short*)d_ws;
    unsigned short* Mb = Xb + (size_t)B_DIM * D_DIM;
    float* xsq = (float*)(Mb + (size_t)S_DIM * D_DIM);
    float* msq = xsq + B_DIM;

    prep_kernel<<<(B_DIM + S_DIM) / 4, 256, 0, stream>>>(X, Mx, Xb, Mb, xsq, msq);

    dim3 grid(S_DIM / BN, B_DIM / BM);  // (16, 32) = 512 blocks -> 2/CU
    gemm_kernel<<<grid, 512, 0, stream>>>(Xb, Mb, xsq, msq, out);
}